// Round 1
// baseline (1488.585 us; speedup 1.0000x reference)
//
#include <hip/hip_runtime.h>

// LSTM_52922587021316 — Round 1: correct scalar fp32 baseline.
// 1 thread = 1 batch element. h1/h2 const-indexed (VGPRs); c1/c2/hn scratch.
// Weights read via thread-uniform indices -> scalar loads (s_load_dwordx*).

#define HID 32
#define TSTEPS 7

__device__ __forceinline__ float fast_rcp(float x) {
    return __builtin_amdgcn_rcpf(x);
}

__device__ __forceinline__ float sigm(float x) {
    // 1/(1+exp(-x)); exp(-x)->inf for very negative x gives 1/inf = 0 (correct)
    return fast_rcp(1.0f + __expf(-x));
}

__device__ __forceinline__ float tanh_fast(float x) {
    x = fminf(fmaxf(x, -15.0f), 15.0f);   // avoid inf/inf
    float e = __expf(2.0f * x);
    return (e - 1.0f) * fast_rcp(e + 1.0f);
}

__global__ __launch_bounds__(256) void lstm2_fused(
    const float* __restrict__ xin,   // [B, 7]
    const float* __restrict__ Wih0,  // [128, 1]
    const float* __restrict__ Whh0,  // [128, 32]
    const float* __restrict__ bih0,  // [128]
    const float* __restrict__ bhh0,  // [128]
    const float* __restrict__ Wih1,  // [128, 32]
    const float* __restrict__ Whh1,  // [128, 32]
    const float* __restrict__ bih1,  // [128]
    const float* __restrict__ bhh1,  // [128]
    const float* __restrict__ fcw,   // [32]
    const float* __restrict__ fcb,   // [1]
    const float* __restrict__ fc1w,  // [7]
    const float* __restrict__ fc1b,  // [1]
    float* __restrict__ out,         // [B]
    int B)
{
    const int b = blockIdx.x * blockDim.x + threadIdx.x;
    if (b >= B) return;

    // register-resident states (const-indexed only)
    float h1[HID], h2[HID];
    // dynamically indexed -> scratch (small, L1-resident)
    float c1[HID], c2[HID], hn[HID];

#pragma unroll
    for (int j = 0; j < HID; ++j) {
        h1[j] = 0.0f; h2[j] = 0.0f; c1[j] = 0.0f; c2[j] = 0.0f;
    }

    float acc = fc1b[0];
    const float fcb0 = fcb[0];

    for (int t = 0; t < TSTEPS; ++t) {
        const float xt = xin[b * TSTEPS + t];

        // ---------------- layer 0: gates = b + Wih0*x + Whh0 @ h1 ----------
#pragma unroll 1
        for (int j = 0; j < HID; ++j) {
            float gi = bih0[j]           + bhh0[j]           + Wih0[j]           * xt;
            float gf = bih0[HID + j]     + bhh0[HID + j]     + Wih0[HID + j]     * xt;
            float gg = bih0[2 * HID + j] + bhh0[2 * HID + j] + Wih0[2 * HID + j] * xt;
            float go = bih0[3 * HID + j] + bhh0[3 * HID + j] + Wih0[3 * HID + j] * xt;
            const float* wi = Whh0 + j * HID;
            const float* wf = Whh0 + (HID + j) * HID;
            const float* wg = Whh0 + (2 * HID + j) * HID;
            const float* wo = Whh0 + (3 * HID + j) * HID;
#pragma unroll
            for (int k = 0; k < HID; ++k) {
                const float hk = h1[k];
                gi = fmaf(wi[k], hk, gi);
                gf = fmaf(wf[k], hk, gf);
                gg = fmaf(wg[k], hk, gg);
                go = fmaf(wo[k], hk, go);
            }
            const float ii = sigm(gi);
            const float ff = sigm(gf);
            const float gv = tanh_fast(gg);
            const float oo = sigm(go);
            const float c  = ff * c1[j] + ii * gv;
            c1[j] = c;
            hn[j] = oo * tanh_fast(c);
        }
        // commit new h1 into registers
#pragma unroll
        for (int k = 0; k < HID; ++k) h1[k] = hn[k];

        // ---------------- layer 1: gates = b + Wih1 @ h1new + Whh1 @ h2 ----
#pragma unroll 1
        for (int j = 0; j < HID; ++j) {
            float gi = bih1[j]           + bhh1[j];
            float gf = bih1[HID + j]     + bhh1[HID + j];
            float gg = bih1[2 * HID + j] + bhh1[2 * HID + j];
            float go = bih1[3 * HID + j] + bhh1[3 * HID + j];
            const float* ui = Wih1 + j * HID;
            const float* uf = Wih1 + (HID + j) * HID;
            const float* ug = Wih1 + (2 * HID + j) * HID;
            const float* uo = Wih1 + (3 * HID + j) * HID;
            const float* ri = Whh1 + j * HID;
            const float* rf = Whh1 + (HID + j) * HID;
            const float* rg = Whh1 + (2 * HID + j) * HID;
            const float* ro = Whh1 + (3 * HID + j) * HID;
#pragma unroll
            for (int k = 0; k < HID; ++k) {
                const float xk = h1[k];
                const float hk = h2[k];
                gi = fmaf(ui[k], xk, gi);
                gf = fmaf(uf[k], xk, gf);
                gg = fmaf(ug[k], xk, gg);
                go = fmaf(uo[k], xk, go);
                gi = fmaf(ri[k], hk, gi);
                gf = fmaf(rf[k], hk, gf);
                gg = fmaf(rg[k], hk, gg);
                go = fmaf(ro[k], hk, go);
            }
            const float ii = sigm(gi);
            const float ff = sigm(gf);
            const float gv = tanh_fast(gg);
            const float oo = sigm(go);
            const float c  = ff * c2[j] + ii * gv;
            c2[j] = c;
            hn[j] = oo * tanh_fast(c);
        }
#pragma unroll
        for (int k = 0; k < HID; ++k) h2[k] = hn[k];

        // ---------------- fc (H->1) for this timestep, fold into fc1 -------
        float s = fcb0;
#pragma unroll
        for (int k = 0; k < HID; ++k) s = fmaf(fcw[k], h2[k], s);
        acc = fmaf(fc1w[t], s, acc);
    }

    out[b] = acc;
}

extern "C" void kernel_launch(void* const* d_in, const int* in_sizes, int n_in,
                              void* d_out, int out_size, void* d_ws, size_t ws_size,
                              hipStream_t stream) {
    const float* xin  = (const float*)d_in[0];
    const float* Wih0 = (const float*)d_in[1];
    const float* Whh0 = (const float*)d_in[2];
    const float* bih0 = (const float*)d_in[3];
    const float* bhh0 = (const float*)d_in[4];
    const float* Wih1 = (const float*)d_in[5];
    const float* Whh1 = (const float*)d_in[6];
    const float* bih1 = (const float*)d_in[7];
    const float* bhh1 = (const float*)d_in[8];
    const float* fcw  = (const float*)d_in[9];
    const float* fcb  = (const float*)d_in[10];
    const float* fc1w = (const float*)d_in[11];
    const float* fc1b = (const float*)d_in[12];
    float* out = (float*)d_out;

    const int B = in_sizes[0] / TSTEPS;   // [B, T, F=1]
    const int block = 256;
    const int grid = (B + block - 1) / block;
    lstm2_fused<<<grid, block, 0, stream>>>(
        xin, Wih0, Whh0, bih0, bhh0, Wih1, Whh1, bih1, bhh1,
        fcw, fcb, fc1w, fc1b, out, B);
}

// Round 2
// 281.056 us; speedup vs baseline: 5.2964x; 5.2964x over previous
//
#include <hip/hip_runtime.h>

// LSTM_52922587021316 — Round 2: MFMA f16 reformulation.
// 1 wave = 16 sequences. Per t: gates[16,128] = A[16,K] @ B[K,128] via
// mfma_f32_16x16x32_f16 (8 MFMAs layer0, 16 MFMAs layer1). Gate quads land
// in-lane in C-layout -> elementwise cell update in fp32 regs. h transposed
// C-layout -> A-layout via per-wave LDS (b16 writes, b128 read, lgkmcnt fence,
// no barrier). fc+fc1 folded into per-lane partials, butterfly-reduced once.

#define HID 32
#define TSTEPS 7
#define LSTRIDE 40   // halves per LDS row: 32 + 8 pad (80 B, 16B-aligned rows)

typedef _Float16 half8 __attribute__((ext_vector_type(8)));
typedef float floatx4 __attribute__((ext_vector_type(4)));

__device__ __forceinline__ float fast_rcp(float x) { return __builtin_amdgcn_rcpf(x); }
__device__ __forceinline__ float sigm(float x) { return fast_rcp(1.0f + __expf(-x)); }
__device__ __forceinline__ float tanh_fast(float x) {
    x = fminf(fmaxf(x, -15.0f), 15.0f);
    float e = __expf(2.0f * x);
    return (e - 1.0f) * fast_rcp(e + 1.0f);
}
__device__ __forceinline__ void lds_fence() {
    asm volatile("s_waitcnt lgkmcnt(0)" ::: "memory");
}

__global__ __launch_bounds__(256, 2) void lstm2_mfma(
    const float* __restrict__ xin,   // [B, 7]
    const float* __restrict__ Wih0,  // [128, 1]
    const float* __restrict__ Whh0,  // [128, 32]
    const float* __restrict__ bih0,  // [128]
    const float* __restrict__ bhh0,  // [128]
    const float* __restrict__ Wih1,  // [128, 32]
    const float* __restrict__ Whh1,  // [128, 32]
    const float* __restrict__ bih1,  // [128]
    const float* __restrict__ bhh1,  // [128]
    const float* __restrict__ fcw,   // [32]
    const float* __restrict__ fcb,   // [1]
    const float* __restrict__ fc1w,  // [7]
    const float* __restrict__ fc1b,  // [1]
    float* __restrict__ out,         // [B]
    int B)
{
    const int lane = threadIdx.x & 63;
    const int wave = threadIdx.x >> 6;
    const int col  = lane & 15;          // C-layout col / A-layout row m
    const int rg   = lane >> 4;          // quad: C rows rg*4..rg*4+3, A k-group rg*8..rg*8+7
    const int seq_base = (blockIdx.x * 4 + wave) * 16;

    __shared__ __align__(16) _Float16 lds[4][2][16 * LSTRIDE];
    _Float16* h1l = &lds[wave][0][0];
    _Float16* h2l = &lds[wave][1][0];

    // ---- preload weights as f16 B-fragments (B^T == [n][k] row-major) ----
    // b_frag[j] = W[n = nt*16+col][k = rg*8+j]
    half8 B0[8], B1a[8], B1b[8];
#pragma unroll
    for (int nt = 0; nt < 8; ++nt) {
        const int n = nt * 16 + col;
        const float* s0 = Whh0 + n * HID + rg * 8;
        const float* s1 = Wih1 + n * HID + rg * 8;
        const float* s2 = Whh1 + n * HID + rg * 8;
#pragma unroll
        for (int j = 0; j < 8; ++j) {
            B0[nt][j]  = (_Float16)s0[j];
            B1a[nt][j] = (_Float16)s1[j];
            B1b[nt][j] = (_Float16)s2[j];
        }
    }
    // per-lane bias / rank-1 coefficients (depend on col only)
    float b0s[8], b1s[8], wx[8];
#pragma unroll
    for (int nt = 0; nt < 8; ++nt) {
        const int n = nt * 16 + col;
        b0s[nt] = bih0[n] + bhh0[n];
        b1s[nt] = bih1[n] + bhh1[n];
        wx[nt]  = Wih0[n];
    }
    const float fcw_l0 = fcw[col];
    const float fcw_l1 = fcw[16 + col];

    half8 Ah1 = {};      // h1 in A-layout (zero at t=0)
    half8 Ah2 = {};      // h2 in A-layout
    float c1[2][4] = {}, c2[2][4] = {};
    float facc[4] = {0.f, 0.f, 0.f, 0.f};

    for (int t = 0; t < TSTEPS; ++t) {
        // x for my 4 rows (m = rg*4 + r)
        float xr[4];
#pragma unroll
        for (int r = 0; r < 4; ++r)
            xr[r] = xin[(seq_base + rg * 4 + r) * TSTEPS + t];

        // -------- layer 0: gates = bias + h1_prev @ Whh0^T (+ x*Wih0) -----
        floatx4 g0[8];
#pragma unroll
        for (int nt = 0; nt < 8; ++nt) {
            floatx4 c = {b0s[nt], b0s[nt], b0s[nt], b0s[nt]};
            g0[nt] = __builtin_amdgcn_mfma_f32_16x16x32_f16(Ah1, B0[nt], c, 0, 0, 0);
        }
#pragma unroll
        for (int nt = 0; nt < 8; ++nt)
#pragma unroll
            for (int r = 0; r < 4; ++r)
                g0[nt][r] = fmaf(wx[nt], xr[r], g0[nt][r]);

        // epilogue 0: cell update, write h1_new to LDS
#pragma unroll
        for (int q = 0; q < 2; ++q) {
#pragma unroll
            for (int r = 0; r < 4; ++r) {
                const float ii = sigm(g0[0 + q][r]);
                const float ff = sigm(g0[2 + q][r]);
                const float gg = tanh_fast(g0[4 + q][r]);
                const float oo = sigm(g0[6 + q][r]);
                const float c  = ff * c1[q][r] + ii * gg;
                c1[q][r] = c;
                const float h = oo * tanh_fast(c);
                h1l[(rg * 4 + r) * LSTRIDE + q * 16 + col] = (_Float16)h;
            }
        }
        lds_fence();
        Ah1 = *(const half8*)&h1l[col * LSTRIDE + rg * 8];

        // -------- layer 1: gates = bias + h1_new @ Wih1^T + h2_prev @ Whh1^T
        floatx4 g1[8];
#pragma unroll
        for (int nt = 0; nt < 8; ++nt) {
            floatx4 c = {b1s[nt], b1s[nt], b1s[nt], b1s[nt]};
            c = __builtin_amdgcn_mfma_f32_16x16x32_f16(Ah1, B1a[nt], c, 0, 0, 0);
            g1[nt] = __builtin_amdgcn_mfma_f32_16x16x32_f16(Ah2, B1b[nt], c, 0, 0, 0);
        }

        // epilogue 1: cell update, fc partial, write h2_new to LDS
        const float f1t = fc1w[t];
        const float w0 = f1t * fcw_l0;
        const float w1 = f1t * fcw_l1;
#pragma unroll
        for (int q = 0; q < 2; ++q) {
            const float wq = q ? w1 : w0;
#pragma unroll
            for (int r = 0; r < 4; ++r) {
                const float ii = sigm(g1[0 + q][r]);
                const float ff = sigm(g1[2 + q][r]);
                const float gg = tanh_fast(g1[4 + q][r]);
                const float oo = sigm(g1[6 + q][r]);
                const float c  = ff * c2[q][r] + ii * gg;
                c2[q][r] = c;
                const float h = oo * tanh_fast(c);
                facc[r] = fmaf(wq, h, facc[r]);
                h2l[(rg * 4 + r) * LSTRIDE + q * 16 + col] = (_Float16)h;
            }
        }
        lds_fence();
        Ah2 = *(const half8*)&h2l[col * LSTRIDE + rg * 8];
    }

    // ---- reduce fc partials across the 16 cols, add constant tail --------
#pragma unroll
    for (int r = 0; r < 4; ++r) {
        float v = facc[r];
        v += __shfl_xor(v, 1);
        v += __shfl_xor(v, 2);
        v += __shfl_xor(v, 4);
        v += __shfl_xor(v, 8);
        facc[r] = v;
    }
    float sum_f1 = 0.f;
#pragma unroll
    for (int t = 0; t < TSTEPS; ++t) sum_f1 += fc1w[t];
    const float tail = fcb[0] * sum_f1 + fc1b[0];

    if (col == 0) {
#pragma unroll
        for (int r = 0; r < 4; ++r)
            out[seq_base + rg * 4 + r] = facc[r] + tail;
    }
}

extern "C" void kernel_launch(void* const* d_in, const int* in_sizes, int n_in,
                              void* d_out, int out_size, void* d_ws, size_t ws_size,
                              hipStream_t stream) {
    const float* xin  = (const float*)d_in[0];
    const float* Wih0 = (const float*)d_in[1];
    const float* Whh0 = (const float*)d_in[2];
    const float* bih0 = (const float*)d_in[3];
    const float* bhh0 = (const float*)d_in[4];
    const float* Wih1 = (const float*)d_in[5];
    const float* Whh1 = (const float*)d_in[6];
    const float* bih1 = (const float*)d_in[7];
    const float* bhh1 = (const float*)d_in[8];
    const float* fcw  = (const float*)d_in[9];
    const float* fcb  = (const float*)d_in[10];
    const float* fc1w = (const float*)d_in[11];
    const float* fc1b = (const float*)d_in[12];
    float* out = (float*)d_out;

    const int B = in_sizes[0] / TSTEPS;   // [B, T, F=1]
    // 1 block = 4 waves = 64 sequences
    const int grid = B / 64;
    lstm2_mfma<<<grid, 256, 0, stream>>>(
        xin, Wih0, Whh0, bih0, bhh0, Wih1, Whh1, bih1, bhh1,
        fcw, fcb, fc1w, fc1b, out, B);
}